// Round 4
// baseline (1074.444 us; speedup 1.0000x reference)
//
#include <hip/hip_runtime.h>

typedef __bf16 bf16x8 __attribute__((ext_vector_type(8)));
typedef float f32x4 __attribute__((ext_vector_type(4)));

#define HH 64
#define WW 64
#define HW 4096
#define COUT 256
#define BSTRIDE 296   // Bs row stride (bf16 elems) = 592 B
#define NROWS 12      // staged input rows [rowbase, rowbase+11]
#define XROW 65       // px slots per staged row (odd -> spread row base banks)
#define XS_OFF 37888  // byte offset of Xs inside smem

// Raw barrier: flush LDS (lgkmcnt) but do NOT drain vmcnt — staging global
// loads stay in flight across the barrier (compiler waits at their uses).
__device__ __forceinline__ void bar_sync() {
    asm volatile("s_waitcnt lgkmcnt(0)" ::: "memory");
    __builtin_amdgcn_s_barrier();
    asm volatile("" ::: "memory");
}

// ---------------------------------------------------------------------------
// Kernel 1: blend circle weights -> bf16, pre-fragmented MFMA A layout.
// Thread = (tap, cg, tm, lane) emits ONE 16B fragment (tap block-uniform).
// ---------------------------------------------------------------------------
__global__ __launch_bounds__(256) void prep_weights(const float* __restrict__ weight,
                                                    __bf16* __restrict__ wp) {
    const int t = blockIdx.x * 256 + threadIdx.x;
    const int lane = t & 63;
    const int tm   = (t >> 6) & 15;
    const int cg   = (t >> 10) & 7;
    const int tap  = t >> 13;              // 0..8, block-uniform
    const int rr = lane & 15, q = lane >> 4;
    const int o  = tm * 16 + rr;
    const int c0 = cg * 32 + q * 8;
    const float* wb = weight + ((size_t)o * 256 + c0) * 9;
    const float Af = 0.70710678118654752f;
    const float Bf = 1.0f - Af;
    bf16x8 v;
    #pragma unroll
    for (int j = 0; j < 8; ++j) {
        const float* w = wb + j * 9;
        float r;
        switch (tap) {
            case 0:  r = Af*(Af*w[0]+Bf*w[1]) + Bf*(Af*w[3]+Bf*w[4]); break;
            case 1:  r = w[1]; break;
            case 2:  r = Af*(Bf*w[1]+Af*w[2]) + Bf*(Bf*w[4]+Af*w[5]); break;
            case 3:  r = w[3]; break;
            case 4:  r = w[4]; break;
            case 5:  r = w[5]; break;
            case 6:  r = Bf*(Af*w[3]+Bf*w[4]) + Af*(Af*w[6]+Bf*w[7]); break;
            case 7:  r = w[7]; break;
            default: r = Bf*(Bf*w[4]+Af*w[5]) + Af*(Bf*w[7]+Af*w[8]); break;
        }
        v[j] = (__bf16)r;
    }
    const int ksg = cg * 9 + tap;
    *(bf16x8*)&wp[(size_t)(((ksg * 16 + tm) << 6) | lane) << 3] = v;
}

// ---------------------------------------------------------------------------
// Kernel 2: pipelined LDS-staged bilinear-sample + implicit GEMM.
// 256 blocks x 1024 thr (16 waves, 4/SIMD). Tile M=256 x N=64 (one image row).
// Wave = (mg 0..3) x (ng 0..1) x (klq 0..1): acc[4][2], kl 5+4 split.
// Staging: slot-based b128 Xs writes (conflict-free), coalesced global loads.
// ---------------------------------------------------------------------------
__global__ __launch_bounds__(1024) void dcn_main(
        const float* __restrict__ x, const float* __restrict__ off,
        const float* __restrict__ msk, const __bf16* __restrict__ wp,
        const float* __restrict__ bias, float* __restrict__ out) {
    __shared__ char smem[65536];   // Bs[0..37887] | Xs[37888..62847]; epi: f32 scratch
    __bf16* Xs = (__bf16*)(smem + XS_OFF);
    char* BsB  = smem;
    const char* XsB = (const char*)smem + XS_OFF;

    const int tid  = threadIdx.x;
    const int wv   = tid >> 6;
    const int lane = tid & 63;
    const int q    = lane >> 4, rr = lane & 15;
    const int px   = lane;

    const int mg  = wv & 3;
    const int ng  = (wv >> 2) & 1;
    const int klq = wv >> 3;
    const int klbeg = klq ? 5 : 0;
    const int nkl   = klq ? 4 : 5;

    const int bid = blockIdx.x;
    const int xcd = bid & 7;
    const int b   = xcd >> 1;
    const int h   = ((xcd & 1) << 5) | (bid >> 3);

    const int rowbase = min(max(h - 5, 0), HH - NROWS);
    const float* xb = x + (size_t)b * 256 * HW;

    // ---- staging slot geometry (slotA = tid; slotB = tid+1024 if tid<512) --
    const int sgA  = (tid >= 768) ? 1 : 0;
    const int rowA = (tid - sgA * 768) >> 6;
    const bool has2 = (tid < 512);
    const int rowB = wv + 4;                       // sg = 1
    const int XaA = ((sgA * NROWS + rowA) * XROW + lane) << 3;   // bf16 elems
    const int XaB = ((NROWS + rowB) * XROW + lane) << 3;
    const int gA = (rowbase + rowA) * 64 + lane;
    const int gB = (rowbase + rowB) * 64 + lane;

    // ---- per-thread gather-unit params, computed ONCE ---------------------
    // unit k=0: c = wv (0..15); k=1 (waves 0,1 only): c = 16 + wv.
    float W00[2], W01[2], W10[2], W11[2];
    int AY0[2], AY1[2], DXO[2], COLB[2], GP[2];
    const bool UV1 = (wv < 2);
    #pragma unroll
    for (int k = 0; k < 2; ++k) {
        if (k == 0 || UV1) {
            int c = (k == 0) ? wv : (16 + wv);
            int sg = c / 9, tap = c % 9;
            int ki = tap / 3, kj = tap - 3 * ki;
            const float* offp = off + (size_t)b * 18 * HW + h * 64 + px;
            float dy = offp[(2 * tap) * HW];
            float dx = offp[(2 * tap + 1) * HW];
            float mv = msk[(size_t)b * 9 * HW + (size_t)tap * HW + h * 64 + px];
            float py  = (float)(h - 1 + ki) + dy;
            float pxf = (float)(px - 1 + kj) + dx;
            float y0f = floorf(py), x0f = floorf(pxf);
            float ly = py - y0f, lx = pxf - x0f;
            float hy = 1.0f - ly, hx = 1.0f - lx;
            int y0 = (int)y0f, x0 = (int)x0f;
            int y1 = y0 + 1, x1 = x0 + 1;
            bool vy0 = (y0 >= 0) && (y0 < HH), vy1 = (y1 >= 0) && (y1 < HH);
            bool vx0 = (x0 >= 0) && (x0 < WW), vx1 = (x1 >= 0) && (x1 < WW);
            int cy0 = min(max(y0, 0), HH - 1), cy1 = min(max(y1, 0), HH - 1);
            int cx0 = min(max(x0, 0), WW - 1), cx1 = min(max(x1, 0), WW - 1);
            W00[k] = (vy0 && vx0) ? hy * hx * mv : 0.0f;
            W01[k] = (vy0 && vx1) ? hy * lx * mv : 0.0f;
            W10[k] = (vy1 && vx0) ? ly * hx * mv : 0.0f;
            W11[k] = (vy1 && vx1) ? ly * lx * mv : 0.0f;
            int ry0 = min(max(cy0 - rowbase, 0), NROWS - 1);
            int ry1 = min(max(cy1 - rowbase, 0), NROWS - 1);
            bool useG = (vy0 && (cy0 < rowbase || cy0 > rowbase + NROWS - 1))
                     || (vy1 && (cy1 < rowbase || cy1 > rowbase + NROWS - 1));
            AY0[k]  = ((sg * NROWS + ry0) * XROW + cx0) * 16;
            AY1[k]  = ((sg * NROWS + ry1) * XROW + cx0) * 16;
            DXO[k]  = (cx1 - cx0) * 16;
            COLB[k] = (tap * 32 + sg * 8) * 2;
            GP[k]   = cy0 | (cy1 << 6) | (cx0 << 12) | (cx1 << 18) | (sg << 24)
                    | (useG ? (1u << 31) : 0);
        }
    }

    f32x4 acc[4][2];
    #pragma unroll
    for (int i = 0; i < 4; ++i)
        #pragma unroll
        for (int n = 0; n < 2; ++n)
            acc[i][n] = (f32x4)0.0f;

    // ---- preload stage 0 staging values into regs -------------------------
    float R[2][8];
    {
        const float* pA = xb + (size_t)(sgA * 8) * HW + gA;
        #pragma unroll
        for (int j = 0; j < 8; ++j) R[0][j] = pA[j * HW];
        if (has2) {
            const float* pB = xb + (size_t)8 * HW + gB;
            #pragma unroll
            for (int j = 0; j < 8; ++j) R[1][j] = pB[j * HW];
        }
    }

    #pragma unroll 1
    for (int s = 0; s < 16; ++s) {
        const int cg = s >> 1, half = s & 1;
        bar_sync();   // Xs(s-1) gathers done; Bs(cg-1) MFMA reads done
        // ---- write Xs from regs (one b128 per slot, conflict-free) --------
        {
            bf16x8 vA;
            #pragma unroll
            for (int j = 0; j < 8; ++j) vA[j] = (__bf16)R[0][j];
            *(bf16x8*)&Xs[XaA] = vA;
            if (has2) {
                bf16x8 vB;
                #pragma unroll
                for (int j = 0; j < 8; ++j) vB[j] = (__bf16)R[1][j];
                *(bf16x8*)&Xs[XaB] = vB;
            }
        }
        // ---- issue next stage's global loads (stay in flight) -------------
        if (s < 15) {
            const int s1 = s + 1;
            const int cbase = (s1 >> 1) * 32 + (s1 & 1) * 16;
            const float* pA = xb + (size_t)(cbase + sgA * 8) * HW + gA;
            #pragma unroll
            for (int j = 0; j < 8; ++j) R[0][j] = pA[j * HW];
            if (has2) {
                const float* pB = xb + (size_t)(cbase + 8) * HW + gB;
                #pragma unroll
                for (int j = 0; j < 8; ++j) R[1][j] = pB[j * HW];
            }
        }
        bar_sync();   // Xs ready
        // ---- gather: <=2 (c,px) units per thread --------------------------
        #pragma unroll
        for (int k = 0; k < 2; ++k) {
            if (k == 0 || UV1) {
                bf16x8 c00 = *(const bf16x8*)(XsB + AY0[k]);
                bf16x8 c01 = *(const bf16x8*)(XsB + AY0[k] + DXO[k]);
                bf16x8 c10 = *(const bf16x8*)(XsB + AY1[k]);
                bf16x8 c11 = *(const bf16x8*)(XsB + AY1[k] + DXO[k]);
                float w0 = W00[k], w1 = W01[k], w2 = W10[k], w3 = W11[k];
                bf16x8 res;
                #pragma unroll
                for (int j = 0; j < 8; ++j) {
                    float v = w0 * (float)c00[j] + w1 * (float)c01[j]
                            + w2 * (float)c10[j] + w3 * (float)c11[j];
                    res[j] = (__bf16)v;
                }
                int gp = GP[k];
                if (gp < 0) {   // rare: valid corner outside staged rows
                    int cy0 = gp & 63, cy1 = (gp >> 6) & 63;
                    int cx0 = (gp >> 12) & 63, cx1 = (gp >> 18) & 63;
                    int sg = (gp >> 24) & 3;
                    const float* xc = xb + (size_t)(cg * 32 + half * 16 + sg * 8) * HW;
                    int i00 = cy0 * 64 + cx0, i01 = cy0 * 64 + cx1;
                    int i10 = cy1 * 64 + cx0, i11 = cy1 * 64 + cx1;
                    #pragma unroll
                    for (int j = 0; j < 8; ++j) {
                        float v = w0 * xc[i00] + w1 * xc[i01]
                                + w2 * xc[i10] + w3 * xc[i11];
                        res[j] = (__bf16)v;
                        xc += HW;
                    }
                }
                *(bf16x8*)(BsB + px * 592 + COLB[k] + half * 32) = res;
            }
        }
        if (half) {
            bar_sync();   // Bs complete (both halves)
            // ---- MFMA: 4 m-tiles x 2 n-tiles, kl split across wave halves -
            const __bf16* ap = wp + (((size_t)(cg * 9 + klbeg) * 16 + mg * 4) * 64 + lane) * 8;
            bf16x8 a0 = *(const bf16x8*)ap;
            bf16x8 a1 = *(const bf16x8*)(ap + 512);
            bf16x8 a2 = *(const bf16x8*)(ap + 1024);
            bf16x8 a3 = *(const bf16x8*)(ap + 1536);
            int kc = (klbeg * 32 + q * 8) * 2;
            const char* bprow = BsB + (ng * 32 + rr) * 592;
            #pragma unroll 1
            for (int t = 0; t < nkl; ++t) {
                bf16x8 n0 = a0, n1 = a1, n2 = a2, n3 = a3;
                if (t + 1 < nkl) {
                    const __bf16* np = ap + 8192;
                    n0 = *(const bf16x8*)np;
                    n1 = *(const bf16x8*)(np + 512);
                    n2 = *(const bf16x8*)(np + 1024);
                    n3 = *(const bf16x8*)(np + 1536);
                }
                bf16x8 bb0 = *(const bf16x8*)(bprow + kc);
                bf16x8 bb1 = *(const bf16x8*)(bprow + 16 * 592 + kc);
                acc[0][0] = __builtin_amdgcn_mfma_f32_16x16x32_bf16(a0, bb0, acc[0][0], 0, 0, 0);
                acc[1][0] = __builtin_amdgcn_mfma_f32_16x16x32_bf16(a1, bb0, acc[1][0], 0, 0, 0);
                acc[2][0] = __builtin_amdgcn_mfma_f32_16x16x32_bf16(a2, bb0, acc[2][0], 0, 0, 0);
                acc[3][0] = __builtin_amdgcn_mfma_f32_16x16x32_bf16(a3, bb0, acc[3][0], 0, 0, 0);
                acc[0][1] = __builtin_amdgcn_mfma_f32_16x16x32_bf16(a0, bb1, acc[0][1], 0, 0, 0);
                acc[1][1] = __builtin_amdgcn_mfma_f32_16x16x32_bf16(a1, bb1, acc[1][1], 0, 0, 0);
                acc[2][1] = __builtin_amdgcn_mfma_f32_16x16x32_bf16(a2, bb1, acc[2][1], 0, 0, 0);
                acc[3][1] = __builtin_amdgcn_mfma_f32_16x16x32_bf16(a3, bb1, acc[3][1], 0, 0, 0);
                ap += 8192;
                kc += 64;
                a0 = n0; a1 = n1; a2 = n2; a3 = n3;
            }
        }
    }

    // ---- epilogue: one-round kl-partial reduce via LDS, then store --------
    float* scr = (float*)smem;   // Bs/Xs dead; 8 waves x 8 KB = 64 KB exactly
    bar_sync();
    if (klq == 1) {
        const int base = (wv - 8) * 2048 + lane * 4;
        #pragma unroll
        for (int i = 0; i < 4; ++i)
            #pragma unroll
            for (int n = 0; n < 2; ++n)
                *(f32x4*)&scr[base + (i * 2 + n) * 256] = acc[i][n];
    }
    bar_sync();
    if (klq == 0) {
        const int base = wv * 2048 + lane * 4;
        #pragma unroll
        for (int i = 0; i < 4; ++i) {
            #pragma unroll
            for (int n = 0; n < 2; ++n) {
                f32x4 p = *(const f32x4*)&scr[base + (i * 2 + n) * 256];
                #pragma unroll
                for (int e = 0; e < 4; ++e) {
                    int m = (mg * 4 + i) * 16 + q * 4 + e;
                    out[((size_t)b * COUT + m) * HW + h * 64 + ng * 32 + n * 16 + rr]
                        = acc[i][n][e] + p[e] + bias[m];
                }
            }
        }
    }
}

extern "C" void kernel_launch(void* const* d_in, const int* in_sizes, int n_in,
                              void* d_out, int out_size, void* d_ws, size_t ws_size,
                              hipStream_t stream) {
    const float* x      = (const float*)d_in[0];   // [4,256,64,64]
    const float* off    = (const float*)d_in[1];   // [4,18,64,64]
    const float* msk    = (const float*)d_in[2];   // [4,9,64,64]
    const float* weight = (const float*)d_in[3];   // [256,256,3,3]
    const float* bias   = (const float*)d_in[4];   // [256]
    float* out = (float*)d_out;                    // [4,256,64,64]

    __bf16* wp = (__bf16*)d_ws;                    // 589824 bf16 = 1.18 MB

    prep_weights<<<288, 256, 0, stream>>>(weight, wp);
    dcn_main<<<256, 1024, 0, stream>>>(x, off, msk, wp, bias, out);
}

// Round 5
// 209.700 us; speedup vs baseline: 5.1237x; 5.1237x over previous
//
#include <hip/hip_runtime.h>

typedef __bf16 bf16x8 __attribute__((ext_vector_type(8)));
typedef float f32x4 __attribute__((ext_vector_type(4)));

#define HH 64
#define WW 64
#define HW 4096
#define COUT 256
#define BSTRIDE 296   // Bs row stride (bf16 elems) = 592 B
#define NPX 32        // pixels (N) per block
#define NROWS 12      // staged input rows [rowbase, rowbase+11]
#define XROW 65       // px slots per staged row
#define XS_OFF 18944  // byte offset of Xs inside smem (= 32*592 Bs bytes)

// Raw barrier: flush LDS (lgkmcnt) but do NOT drain vmcnt — staging global
// loads stay in flight across the barrier (compiler waits at their uses).
__device__ __forceinline__ void bar_sync() {
    asm volatile("s_waitcnt lgkmcnt(0)" ::: "memory");
    __builtin_amdgcn_s_barrier();
    asm volatile("" ::: "memory");
}

// ---------------------------------------------------------------------------
// Kernel 1: blend circle weights -> bf16, pre-fragmented MFMA A layout.
// Thread = (tap, cg, tm, lane) emits ONE 16B fragment (tap block-uniform).
// ---------------------------------------------------------------------------
__global__ __launch_bounds__(256) void prep_weights(const float* __restrict__ weight,
                                                    __bf16* __restrict__ wp) {
    const int t = blockIdx.x * 256 + threadIdx.x;
    const int lane = t & 63;
    const int tm   = (t >> 6) & 15;
    const int cg   = (t >> 10) & 7;
    const int tap  = t >> 13;              // 0..8, block-uniform
    const int rr = lane & 15, q = lane >> 4;
    const int o  = tm * 16 + rr;
    const int c0 = cg * 32 + q * 8;
    const float* wb = weight + ((size_t)o * 256 + c0) * 9;
    const float Af = 0.70710678118654752f;
    const float Bf = 1.0f - Af;
    bf16x8 v;
    #pragma unroll
    for (int j = 0; j < 8; ++j) {
        const float* w = wb + j * 9;
        float r;
        switch (tap) {
            case 0:  r = Af*(Af*w[0]+Bf*w[1]) + Bf*(Af*w[3]+Bf*w[4]); break;
            case 1:  r = w[1]; break;
            case 2:  r = Af*(Bf*w[1]+Af*w[2]) + Bf*(Bf*w[4]+Af*w[5]); break;
            case 3:  r = w[3]; break;
            case 4:  r = w[4]; break;
            case 5:  r = w[5]; break;
            case 6:  r = Bf*(Af*w[3]+Bf*w[4]) + Af*(Af*w[6]+Bf*w[7]); break;
            case 7:  r = w[7]; break;
            default: r = Bf*(Bf*w[4]+Af*w[5]) + Af*(Bf*w[7]+Af*w[8]); break;
        }
        v[j] = (__bf16)r;
    }
    const int ksg = cg * 9 + tap;
    *(bf16x8*)&wp[(size_t)(((ksg * 16 + tm) << 6) | lane) << 3] = v;
}

// ---------------------------------------------------------------------------
// Kernel 2: pipelined LDS-staged bilinear-sample + implicit GEMM.
// 512 blocks x 512 thr (8 waves) = 2 blocks/CU for inter-block phase overlap.
// Tile M=256 x N=32 (half image row). Wave = mg(0..3) x klq(0..1): acc[4][2],
// kl split 5+4, LDS-reduced in epilogue. Slot-based b128 staging (no conflicts).
// ---------------------------------------------------------------------------
__global__ __launch_bounds__(512, 4) void dcn_main(
        const float* __restrict__ x, const float* __restrict__ off,
        const float* __restrict__ msk, const __bf16* __restrict__ wp,
        const float* __restrict__ bias, float* __restrict__ out) {
    __shared__ char smem[43904];   // Bs[0..18943] | Xs[18944..43903]; epi: f32 scratch
    __bf16* Xs = (__bf16*)(smem + XS_OFF);
    char* BsB  = smem;
    const char* XsB = (const char*)smem + XS_OFF;

    const int tid  = threadIdx.x;
    const int wv   = tid >> 6;
    const int lane = tid & 63;
    const int q    = lane >> 4, rr = lane & 15;

    const int mg  = wv & 3;
    const int klq = wv >> 2;
    const int klbeg = klq ? 5 : 0;
    const int nkl   = klq ? 4 : 5;

    // 512 blocks: xcd = bid&7; 2 XCDs per image; u covers (h-half, nh).
    const int bid = blockIdx.x;
    const int xcd = bid & 7;
    const int u   = bid >> 3;                 // 0..63
    const int b   = xcd >> 1;
    const int h   = ((xcd & 1) << 5) | (u >> 1);
    const int nh  = u & 1;                    // which half-row
    const int px0 = nh * 32;

    const int rowbase = min(max(h - 5, 0), HH - NROWS);
    const float* xb = x + (size_t)b * 256 * HW;

    // ---- staging slot geometry: 3 slots/thread, lane-contiguous -----------
    int SGk[3], GOFF[3], XA[3];
    #pragma unroll
    for (int k = 0; k < 3; ++k) {
        int slot = k * 512 + tid;             // 0..1535
        int sg   = slot / 768;
        int rem  = slot - sg * 768;
        int row  = rem >> 6, spx = rem & 63;
        SGk[k]  = sg;
        GOFF[k] = (rowbase + row) * 64 + spx;
        XA[k]   = ((sg * NROWS + row) * XROW + spx) << 3;   // bf16 elem index
    }

    // ---- per-thread gather-unit params, computed ONCE ---------------------
    // px = lane&31, sel = lane>>5. k=0: c = wv*2+sel (0..15); k=1 (wv==0): c=16+sel.
    const int px  = lane & 31;
    const int sel = lane >> 5;
    float W00[2], W01[2], W10[2], W11[2];
    int AY0[2], AY1[2], DXO[2], COLB[2], GP[2];
    const bool UV1 = (wv == 0);
    #pragma unroll
    for (int k = 0; k < 2; ++k) {
        if (k == 0 || UV1) {
            int c = (k == 0) ? (wv * 2 + sel) : (16 + sel);
            int sg = c / 9, tap = c % 9;
            int ki = tap / 3, kj = tap - 3 * ki;
            int gx = px0 + px;
            const float* offp = off + (size_t)b * 18 * HW + h * 64 + gx;
            float dy = offp[(2 * tap) * HW];
            float dx = offp[(2 * tap + 1) * HW];
            float mv = msk[(size_t)b * 9 * HW + (size_t)tap * HW + h * 64 + gx];
            float py  = (float)(h - 1 + ki) + dy;
            float pxf = (float)(gx - 1 + kj) + dx;
            float y0f = floorf(py), x0f = floorf(pxf);
            float ly = py - y0f, lx = pxf - x0f;
            float hy = 1.0f - ly, hx = 1.0f - lx;
            int y0 = (int)y0f, x0 = (int)x0f;
            int y1 = y0 + 1, x1 = x0 + 1;
            bool vy0 = (y0 >= 0) && (y0 < HH), vy1 = (y1 >= 0) && (y1 < HH);
            bool vx0 = (x0 >= 0) && (x0 < WW), vx1 = (x1 >= 0) && (x1 < WW);
            int cy0 = min(max(y0, 0), HH - 1), cy1 = min(max(y1, 0), HH - 1);
            int cx0 = min(max(x0, 0), WW - 1), cx1 = min(max(x1, 0), WW - 1);
            W00[k] = (vy0 && vx0) ? hy * hx * mv : 0.0f;
            W01[k] = (vy0 && vx1) ? hy * lx * mv : 0.0f;
            W10[k] = (vy1 && vx0) ? ly * hx * mv : 0.0f;
            W11[k] = (vy1 && vx1) ? ly * lx * mv : 0.0f;
            int ry0 = min(max(cy0 - rowbase, 0), NROWS - 1);
            int ry1 = min(max(cy1 - rowbase, 0), NROWS - 1);
            bool useG = (vy0 && (cy0 < rowbase || cy0 > rowbase + NROWS - 1))
                     || (vy1 && (cy1 < rowbase || cy1 > rowbase + NROWS - 1));
            AY0[k]  = ((sg * NROWS + ry0) * XROW + cx0) * 16;
            AY1[k]  = ((sg * NROWS + ry1) * XROW + cx0) * 16;
            DXO[k]  = (cx1 - cx0) * 16;
            COLB[k] = (tap * 32 + sg * 8) * 2;
            GP[k]   = cy0 | (cy1 << 6) | (cx0 << 12) | (cx1 << 18) | (sg << 24)
                    | (useG ? (1u << 31) : 0);
        }
    }

    f32x4 acc[4][2];
    #pragma unroll
    for (int i = 0; i < 4; ++i)
        #pragma unroll
        for (int n = 0; n < 2; ++n)
            acc[i][n] = (f32x4)0.0f;

    // ---- preload stage 0 staging values -----------------------------------
    float R[3][8];
    #pragma unroll
    for (int k = 0; k < 3; ++k) {
        const float* p = xb + (size_t)(SGk[k] * 8) * HW + GOFF[k];
        #pragma unroll
        for (int j = 0; j < 8; ++j) R[k][j] = p[j * HW];
    }

    #pragma unroll 1
    for (int s = 0; s < 16; ++s) {
        const int cg = s >> 1, half = s & 1;
        bar_sync();   // Xs(s-1) gathers done; Bs(cg-1) MFMA reads drained
        // ---- write Xs from regs (3 lane-contiguous b128, conflict-free) ---
        #pragma unroll
        for (int k = 0; k < 3; ++k) {
            bf16x8 v;
            #pragma unroll
            for (int j = 0; j < 8; ++j) v[j] = (__bf16)R[k][j];
            *(bf16x8*)&Xs[XA[k]] = v;
        }
        // ---- issue next stage's global loads (stay in flight) -------------
        if (s < 15) {
            const int s1 = s + 1;
            const int cbase = (s1 >> 1) * 32 + (s1 & 1) * 16;
            #pragma unroll
            for (int k = 0; k < 3; ++k) {
                const float* p = xb + (size_t)(cbase + SGk[k] * 8) * HW + GOFF[k];
                #pragma unroll
                for (int j = 0; j < 8; ++j) R[k][j] = p[j * HW];
            }
        }
        bar_sync();   // Xs ready
        // ---- gather: <=2 (c,px) units per thread --------------------------
        #pragma unroll
        for (int k = 0; k < 2; ++k) {
            if (k == 0 || UV1) {
                bf16x8 c00 = *(const bf16x8*)(XsB + AY0[k]);
                bf16x8 c01 = *(const bf16x8*)(XsB + AY0[k] + DXO[k]);
                bf16x8 c10 = *(const bf16x8*)(XsB + AY1[k]);
                bf16x8 c11 = *(const bf16x8*)(XsB + AY1[k] + DXO[k]);
                float w0 = W00[k], w1 = W01[k], w2 = W10[k], w3 = W11[k];
                bf16x8 res;
                #pragma unroll
                for (int j = 0; j < 8; ++j) {
                    float v = w0 * (float)c00[j] + w1 * (float)c01[j]
                            + w2 * (float)c10[j] + w3 * (float)c11[j];
                    res[j] = (__bf16)v;
                }
                int gp = GP[k];
                if (gp < 0) {   // rare: valid corner outside staged rows
                    int cy0 = gp & 63, cy1 = (gp >> 6) & 63;
                    int cx0 = (gp >> 12) & 63, cx1 = (gp >> 18) & 63;
                    int sg = (gp >> 24) & 3;
                    const float* xc = xb + (size_t)(cg * 32 + half * 16 + sg * 8) * HW;
                    int i00 = cy0 * 64 + cx0, i01 = cy0 * 64 + cx1;
                    int i10 = cy1 * 64 + cx0, i11 = cy1 * 64 + cx1;
                    #pragma unroll
                    for (int j = 0; j < 8; ++j) {
                        float v = w0 * xc[i00] + w1 * xc[i01]
                                + w2 * xc[i10] + w3 * xc[i11];
                        res[j] = (__bf16)v;
                        xc += HW;
                    }
                }
                *(bf16x8*)(BsB + px * 592 + COLB[k] + half * 32) = res;
            }
        }
        if (half) {
            bar_sync();   // Bs complete (both halves)
            // ---- MFMA: 4 m-tiles x 2 n-tiles, kl split across wave halves -
            const __bf16* ap = wp + (((size_t)(cg * 9 + klbeg) * 16 + mg * 4) * 64 + lane) * 8;
            bf16x8 a0 = *(const bf16x8*)ap;
            bf16x8 a1 = *(const bf16x8*)(ap + 512);
            bf16x8 a2 = *(const bf16x8*)(ap + 1024);
            bf16x8 a3 = *(const bf16x8*)(ap + 1536);
            int kc = (klbeg * 32 + q * 8) * 2;
            const char* bprow = BsB + rr * 592;
            #pragma unroll 1
            for (int t = 0; t < nkl; ++t) {
                bf16x8 n0 = a0, n1 = a1, n2 = a2, n3 = a3;
                if (t + 1 < nkl) {
                    const __bf16* np = ap + 8192;
                    n0 = *(const bf16x8*)np;
                    n1 = *(const bf16x8*)(np + 512);
                    n2 = *(const bf16x8*)(np + 1024);
                    n3 = *(const bf16x8*)(np + 1536);
                }
                bf16x8 bb0 = *(const bf16x8*)(bprow + kc);
                bf16x8 bb1 = *(const bf16x8*)(bprow + 16 * 592 + kc);
                acc[0][0] = __builtin_amdgcn_mfma_f32_16x16x32_bf16(a0, bb0, acc[0][0], 0, 0, 0);
                acc[1][0] = __builtin_amdgcn_mfma_f32_16x16x32_bf16(a1, bb0, acc[1][0], 0, 0, 0);
                acc[2][0] = __builtin_amdgcn_mfma_f32_16x16x32_bf16(a2, bb0, acc[2][0], 0, 0, 0);
                acc[3][0] = __builtin_amdgcn_mfma_f32_16x16x32_bf16(a3, bb0, acc[3][0], 0, 0, 0);
                acc[0][1] = __builtin_amdgcn_mfma_f32_16x16x32_bf16(a0, bb1, acc[0][1], 0, 0, 0);
                acc[1][1] = __builtin_amdgcn_mfma_f32_16x16x32_bf16(a1, bb1, acc[1][1], 0, 0, 0);
                acc[2][1] = __builtin_amdgcn_mfma_f32_16x16x32_bf16(a2, bb1, acc[2][1], 0, 0, 0);
                acc[3][1] = __builtin_amdgcn_mfma_f32_16x16x32_bf16(a3, bb1, acc[3][1], 0, 0, 0);
                ap += 8192;
                kc += 64;
                a0 = n0; a1 = n1; a2 = n2; a3 = n3;
            }
        }
    }

    // ---- epilogue: one-round kl-partial reduce via LDS, then store --------
    float* scr = (float*)smem;   // Bs/Xs dead; 4 waves x 8 KB = 32 KB
    bar_sync();
    if (klq == 1) {
        const int base = mg * 2048 + lane * 4;
        #pragma unroll
        for (int i = 0; i < 4; ++i)
            #pragma unroll
            for (int n = 0; n < 2; ++n)
                *(f32x4*)&scr[base + (i * 2 + n) * 256] = acc[i][n];
    }
    bar_sync();
    if (klq == 0) {
        const int base = mg * 2048 + lane * 4;
        #pragma unroll
        for (int i = 0; i < 4; ++i) {
            #pragma unroll
            for (int n = 0; n < 2; ++n) {
                f32x4 p = *(const f32x4*)&scr[base + (i * 2 + n) * 256];
                #pragma unroll
                for (int e = 0; e < 4; ++e) {
                    int m = (mg * 4 + i) * 16 + q * 4 + e;
                    out[((size_t)b * COUT + m) * HW + h * 64 + px0 + n * 16 + rr]
                        = acc[i][n][e] + p[e] + bias[m];
                }
            }
        }
    }
}

extern "C" void kernel_launch(void* const* d_in, const int* in_sizes, int n_in,
                              void* d_out, int out_size, void* d_ws, size_t ws_size,
                              hipStream_t stream) {
    const float* x      = (const float*)d_in[0];   // [4,256,64,64]
    const float* off    = (const float*)d_in[1];   // [4,18,64,64]
    const float* msk    = (const float*)d_in[2];   // [4,9,64,64]
    const float* weight = (const float*)d_in[3];   // [256,256,3,3]
    const float* bias   = (const float*)d_in[4];   // [256]
    float* out = (float*)d_out;                    // [4,256,64,64]

    __bf16* wp = (__bf16*)d_ws;                    // 589824 bf16 = 1.18 MB

    prep_weights<<<288, 256, 0, stream>>>(weight, wp);
    dcn_main<<<512, 512, 0, stream>>>(x, off, msk, wp, bias, out);
}

// Round 6
// 123.728 us; speedup vs baseline: 8.6839x; 1.6948x over previous
//
#include <hip/hip_runtime.h>

typedef __bf16 bf16x8 __attribute__((ext_vector_type(8)));
typedef float f32x4 __attribute__((ext_vector_type(4)));

#define HH 64
#define WW 64
#define HW 4096
#define COUT 256
#define BSTRIDE 296   // Bs row stride (bf16 elems) = 592 B
#define NROWS 12      // staged input rows [rowbase, rowbase+11]
#define XROW 65       // px slots per staged row
#define XS_OFF 37888  // byte offset of Xs inside smem (= 64*592 Bs bytes)

// Raw barrier: flush LDS (lgkmcnt) but do NOT drain vmcnt — staging global
// loads stay in flight across the barrier (compiler waits at their uses).
__device__ __forceinline__ void bar_sync() {
    asm volatile("s_waitcnt lgkmcnt(0)" ::: "memory");
    __builtin_amdgcn_s_barrier();
    asm volatile("" ::: "memory");
}

// ---------------------------------------------------------------------------
// Kernel 1: blend circle weights -> bf16, pre-fragmented MFMA A layout.
// Thread = (tap, cg, tm, lane) emits ONE 16B fragment (tap block-uniform).
// ---------------------------------------------------------------------------
__global__ __launch_bounds__(256) void prep_weights(const float* __restrict__ weight,
                                                    __bf16* __restrict__ wp) {
    const int t = blockIdx.x * 256 + threadIdx.x;
    const int lane = t & 63;
    const int tm   = (t >> 6) & 15;
    const int cg   = (t >> 10) & 7;
    const int tap  = t >> 13;              // 0..8, block-uniform
    const int rr = lane & 15, q = lane >> 4;
    const int o  = tm * 16 + rr;
    const int c0 = cg * 32 + q * 8;
    const float* wb = weight + ((size_t)o * 256 + c0) * 9;
    const float Af = 0.70710678118654752f;
    const float Bf = 1.0f - Af;
    bf16x8 v;
    #pragma unroll
    for (int j = 0; j < 8; ++j) {
        const float* w = wb + j * 9;
        float r;
        switch (tap) {
            case 0:  r = Af*(Af*w[0]+Bf*w[1]) + Bf*(Af*w[3]+Bf*w[4]); break;
            case 1:  r = w[1]; break;
            case 2:  r = Af*(Bf*w[1]+Af*w[2]) + Bf*(Bf*w[4]+Af*w[5]); break;
            case 3:  r = w[3]; break;
            case 4:  r = w[4]; break;
            case 5:  r = w[5]; break;
            case 6:  r = Bf*(Af*w[3]+Bf*w[4]) + Af*(Af*w[6]+Bf*w[7]); break;
            case 7:  r = w[7]; break;
            default: r = Bf*(Bf*w[4]+Af*w[5]) + Af*(Bf*w[7]+Af*w[8]); break;
        }
        v[j] = (__bf16)r;
    }
    const int ksg = cg * 9 + tap;
    *(bf16x8*)&wp[(size_t)(((ksg * 16 + tm) << 6) | lane) << 3] = v;
}

// ---------------------------------------------------------------------------
// Kernel 2: pipelined LDS-staged bilinear-sample + implicit GEMM.
// 256 blocks x 512 thr (8 waves, 2/SIMD, 1 block/CU). Tile M=256 x N=64.
// launch_bounds(512,2): 256-reg cap -> ~128 VGPR + 64 AGPR, NO spill (R4/R5
// lesson: a 128 cap forces 64 arch VGPRs and >100 MB of scratch traffic).
// Staging: slot-based lane-contiguous ds_write_b128 (R5-proven, conflict-free).
// MFMA/epilogue: exact R3-proven structure (acc[4][4], kl split 5+4).
// ---------------------------------------------------------------------------
__global__ __launch_bounds__(512, 2) void dcn_main(
        const float* __restrict__ x, const float* __restrict__ off,
        const float* __restrict__ msk, const __bf16* __restrict__ wp,
        const float* __restrict__ bias, float* __restrict__ out) {
    __shared__ char smem[65536];   // Bs[0..37887] | Xs[37888..62847]; epi: f32 scratch
    __bf16* Xs = (__bf16*)(smem + XS_OFF);
    char* BsB  = smem;
    const char* XsB = (const char*)smem + XS_OFF;

    const int tid  = threadIdx.x;
    const int wv   = tid >> 6;
    const int lane = tid & 63;
    const int q    = lane >> 4, rr = lane & 15;
    const int px   = lane;                 // sampling pixel column

    const int bid = blockIdx.x;
    const int xcd = bid & 7;
    const int b   = xcd >> 1;
    const int h   = ((xcd & 1) << 5) | (bid >> 3);

    const int rowbase = min(max(h - 5, 0), HH - NROWS);
    const float* xb = x + (size_t)b * 256 * HW;

    // ---- staging slot geometry: 3 slots/thread, lane-contiguous -----------
    int SGk[3], GOFF[3], XA[3];
    #pragma unroll
    for (int k = 0; k < 3; ++k) {
        int slot = k * 512 + tid;             // 0..1535
        int sg   = slot / 768;
        int rem  = slot - sg * 768;
        int row  = rem >> 6, spx = rem & 63;
        SGk[k]  = sg;
        GOFF[k] = (rowbase + row) * 64 + spx;
        XA[k]   = ((sg * NROWS + row) * XROW + spx) << 3;   // bf16 elem index
    }

    // ---- per-thread gather-unit params, computed ONCE ---------------------
    // unit c (0..17): k=0 -> c=wv; k=1 -> c=wv+8; k=2 -> c=wv+10 (waves 6,7).
    float W00[3], W01[3], W10[3], W11[3];
    int AY0[3], AY1[3], DXO[3], COLB[3], GP[3];
    bool UV[3];
    #pragma unroll
    for (int k = 0; k < 3; ++k) {
        int c = (k < 2) ? (wv + 8 * k) : ((wv >= 6) ? wv + 10 : -1);
        UV[k] = (c >= 0);
        if (UV[k]) {
            int sg = c / 9, tap = c % 9;
            int ki = tap / 3, kj = tap - 3 * ki;
            const float* offp = off + (size_t)b * 18 * HW + h * 64 + px;
            float dy = offp[(2 * tap) * HW];
            float dx = offp[(2 * tap + 1) * HW];
            float mv = msk[(size_t)b * 9 * HW + (size_t)tap * HW + h * 64 + px];
            float py  = (float)(h - 1 + ki) + dy;
            float pxf = (float)(px - 1 + kj) + dx;
            float y0f = floorf(py), x0f = floorf(pxf);
            float ly = py - y0f, lx = pxf - x0f;
            float hy = 1.0f - ly, hx = 1.0f - lx;
            int y0 = (int)y0f, x0 = (int)x0f;
            int y1 = y0 + 1, x1 = x0 + 1;
            bool vy0 = (y0 >= 0) && (y0 < HH), vy1 = (y1 >= 0) && (y1 < HH);
            bool vx0 = (x0 >= 0) && (x0 < WW), vx1 = (x1 >= 0) && (x1 < WW);
            int cy0 = min(max(y0, 0), HH - 1), cy1 = min(max(y1, 0), HH - 1);
            int cx0 = min(max(x0, 0), WW - 1), cx1 = min(max(x1, 0), WW - 1);
            W00[k] = (vy0 && vx0) ? hy * hx * mv : 0.0f;
            W01[k] = (vy0 && vx1) ? hy * lx * mv : 0.0f;
            W10[k] = (vy1 && vx0) ? ly * hx * mv : 0.0f;
            W11[k] = (vy1 && vx1) ? ly * lx * mv : 0.0f;
            int ry0 = min(max(cy0 - rowbase, 0), NROWS - 1);
            int ry1 = min(max(cy1 - rowbase, 0), NROWS - 1);
            bool useG = (vy0 && (cy0 < rowbase || cy0 > rowbase + NROWS - 1))
                     || (vy1 && (cy1 < rowbase || cy1 > rowbase + NROWS - 1));
            AY0[k]  = ((sg * NROWS + ry0) * XROW + cx0) * 16;
            AY1[k]  = ((sg * NROWS + ry1) * XROW + cx0) * 16;
            DXO[k]  = (cx1 - cx0) * 16;
            COLB[k] = (tap * 32 + sg * 8) * 2;
            GP[k]   = cy0 | (cy1 << 6) | (cx0 << 12) | (cx1 << 18) | (sg << 24)
                    | (useG ? (1u << 31) : 0);
        }
    }

    f32x4 acc[4][4];
    #pragma unroll
    for (int i = 0; i < 4; ++i)
        #pragma unroll
        for (int n = 0; n < 4; ++n)
            acc[i][n] = (f32x4)0.0f;

    const int tm0   = (wv & 3) * 4;
    const int klbeg = (wv & 4) ? 5 : 0;
    const int nkl   = (wv & 4) ? 4 : 5;

    // ---- preload stage 0 staging values into regs -------------------------
    float R[3][8];
    #pragma unroll
    for (int k = 0; k < 3; ++k) {
        const float* p = xb + (size_t)(SGk[k] * 8) * HW + GOFF[k];
        #pragma unroll
        for (int j = 0; j < 8; ++j) R[k][j] = p[j * HW];
    }

    #pragma unroll 1
    for (int s = 0; s < 16; ++s) {
        const int cg = s >> 1, half = s & 1;
        bar_sync();   // Xs(s-1) gathers done; Bs(cg-1) MFMA reads done
        // ---- write Xs from regs (3 lane-contiguous b128, conflict-free) ---
        #pragma unroll
        for (int k = 0; k < 3; ++k) {
            bf16x8 v;
            #pragma unroll
            for (int j = 0; j < 8; ++j) v[j] = (__bf16)R[k][j];
            *(bf16x8*)&Xs[XA[k]] = v;
        }
        // ---- issue next stage's global loads (stay in flight) -------------
        if (s < 15) {
            const int s1 = s + 1;
            const int cbase = (s1 >> 1) * 32 + (s1 & 1) * 16;
            #pragma unroll
            for (int k = 0; k < 3; ++k) {
                const float* p = xb + (size_t)(cbase + SGk[k] * 8) * HW + GOFF[k];
                #pragma unroll
                for (int j = 0; j < 8; ++j) R[k][j] = p[j * HW];
            }
        }
        bar_sync();   // Xs ready
        // ---- gather: <=3 (c,px) units per thread --------------------------
        #pragma unroll
        for (int k = 0; k < 3; ++k) {
            if (UV[k]) {
                bf16x8 c00 = *(const bf16x8*)(XsB + AY0[k]);
                bf16x8 c01 = *(const bf16x8*)(XsB + AY0[k] + DXO[k]);
                bf16x8 c10 = *(const bf16x8*)(XsB + AY1[k]);
                bf16x8 c11 = *(const bf16x8*)(XsB + AY1[k] + DXO[k]);
                float w0 = W00[k], w1 = W01[k], w2 = W10[k], w3 = W11[k];
                bf16x8 res;
                #pragma unroll
                for (int j = 0; j < 8; ++j) {
                    float v = w0 * (float)c00[j] + w1 * (float)c01[j]
                            + w2 * (float)c10[j] + w3 * (float)c11[j];
                    res[j] = (__bf16)v;
                }
                int gp = GP[k];
                if (gp < 0) {   // rare: valid corner outside staged rows
                    int cy0 = gp & 63, cy1 = (gp >> 6) & 63;
                    int cx0 = (gp >> 12) & 63, cx1 = (gp >> 18) & 63;
                    int sg = (gp >> 24) & 3;
                    const float* xc = xb + (size_t)(cg * 32 + half * 16 + sg * 8) * HW;
                    int i00 = cy0 * 64 + cx0, i01 = cy0 * 64 + cx1;
                    int i10 = cy1 * 64 + cx0, i11 = cy1 * 64 + cx1;
                    #pragma unroll
                    for (int j = 0; j < 8; ++j) {
                        float v = w0 * xc[i00] + w1 * xc[i01]
                                + w2 * xc[i10] + w3 * xc[i11];
                        res[j] = (__bf16)v;
                        xc += HW;
                    }
                }
                *(bf16x8*)(BsB + px * 592 + COLB[k] + half * 32) = res;
            }
        }
        if (half) {
            bar_sync();   // Bs complete (both halves)
            // ---- MFMA: M=64/wave, 4 n-tiles, kl split across wave halves --
            const __bf16* ap = wp + ((size_t)((cg * 9 + klbeg) * 16 + tm0) * 64 + lane) * 8;
            bf16x8 a0 = *(const bf16x8*)ap;
            bf16x8 a1 = *(const bf16x8*)(ap + 512);
            bf16x8 a2 = *(const bf16x8*)(ap + 1024);
            bf16x8 a3 = *(const bf16x8*)(ap + 1536);
            int kc = (klbeg * 32 + q * 8) * 2;   // byte col in Bs row
            #pragma unroll 1
            for (int t = 0; t < nkl; ++t) {
                bf16x8 n0 = a0, n1 = a1, n2 = a2, n3 = a3;
                if (t + 1 < nkl) {
                    const __bf16* np = ap + 8192;
                    n0 = *(const bf16x8*)np;
                    n1 = *(const bf16x8*)(np + 512);
                    n2 = *(const bf16x8*)(np + 1024);
                    n3 = *(const bf16x8*)(np + 1536);
                }
                const char* bp = BsB + rr * 592 + kc;
                bf16x8 bb0 = *(const bf16x8*)(bp);
                bf16x8 bb1 = *(const bf16x8*)(bp + 16 * 592);
                bf16x8 bb2 = *(const bf16x8*)(bp + 32 * 592);
                bf16x8 bb3 = *(const bf16x8*)(bp + 48 * 592);
                acc[0][0] = __builtin_amdgcn_mfma_f32_16x16x32_bf16(a0, bb0, acc[0][0], 0, 0, 0);
                acc[1][0] = __builtin_amdgcn_mfma_f32_16x16x32_bf16(a1, bb0, acc[1][0], 0, 0, 0);
                acc[2][0] = __builtin_amdgcn_mfma_f32_16x16x32_bf16(a2, bb0, acc[2][0], 0, 0, 0);
                acc[3][0] = __builtin_amdgcn_mfma_f32_16x16x32_bf16(a3, bb0, acc[3][0], 0, 0, 0);
                acc[0][1] = __builtin_amdgcn_mfma_f32_16x16x32_bf16(a0, bb1, acc[0][1], 0, 0, 0);
                acc[1][1] = __builtin_amdgcn_mfma_f32_16x16x32_bf16(a1, bb1, acc[1][1], 0, 0, 0);
                acc[2][1] = __builtin_amdgcn_mfma_f32_16x16x32_bf16(a2, bb1, acc[2][1], 0, 0, 0);
                acc[3][1] = __builtin_amdgcn_mfma_f32_16x16x32_bf16(a3, bb1, acc[3][1], 0, 0, 0);
                acc[0][2] = __builtin_amdgcn_mfma_f32_16x16x32_bf16(a0, bb2, acc[0][2], 0, 0, 0);
                acc[1][2] = __builtin_amdgcn_mfma_f32_16x16x32_bf16(a1, bb2, acc[1][2], 0, 0, 0);
                acc[2][2] = __builtin_amdgcn_mfma_f32_16x16x32_bf16(a2, bb2, acc[2][2], 0, 0, 0);
                acc[3][2] = __builtin_amdgcn_mfma_f32_16x16x32_bf16(a3, bb2, acc[3][2], 0, 0, 0);
                acc[0][3] = __builtin_amdgcn_mfma_f32_16x16x32_bf16(a0, bb3, acc[0][3], 0, 0, 0);
                acc[1][3] = __builtin_amdgcn_mfma_f32_16x16x32_bf16(a1, bb3, acc[1][3], 0, 0, 0);
                acc[2][3] = __builtin_amdgcn_mfma_f32_16x16x32_bf16(a2, bb3, acc[2][3], 0, 0, 0);
                acc[3][3] = __builtin_amdgcn_mfma_f32_16x16x32_bf16(a3, bb3, acc[3][3], 0, 0, 0);
                ap += 8192;
                kc += 64;
                a0 = n0; a1 = n1; a2 = n2; a3 = n3;
            }
        }
    }

    // ---- epilogue: cross-wave kl-partial reduce via LDS, then store -------
    float* scr = (float*)smem;   // Bs/Xs dead now
    bar_sync();
    if (wv >= 4) {
        const int base = (wv - 4) * 4096 + lane * 4;
        #pragma unroll
        for (int i = 0; i < 4; ++i)
            #pragma unroll
            for (int n = 0; n < 4; ++n)
                *(f32x4*)&scr[base + (i * 4 + n) * 256] = acc[i][n];
    }
    bar_sync();
    if (wv < 4) {
        const int mrow = wv * 64;
        const int base = wv * 4096 + lane * 4;
        #pragma unroll
        for (int i = 0; i < 4; ++i) {
            #pragma unroll
            for (int n = 0; n < 4; ++n) {
                f32x4 p = *(const f32x4*)&scr[base + (i * 4 + n) * 256];
                #pragma unroll
                for (int e = 0; e < 4; ++e) {
                    int m = mrow + i * 16 + q * 4 + e;
                    out[((size_t)b * COUT + m) * HW + h * 64 + n * 16 + rr]
                        = acc[i][n][e] + p[e] + bias[m];
                }
            }
        }
    }
}

extern "C" void kernel_launch(void* const* d_in, const int* in_sizes, int n_in,
                              void* d_out, int out_size, void* d_ws, size_t ws_size,
                              hipStream_t stream) {
    const float* x      = (const float*)d_in[0];   // [4,256,64,64]
    const float* off    = (const float*)d_in[1];   // [4,18,64,64]
    const float* msk    = (const float*)d_in[2];   // [4,9,64,64]
    const float* weight = (const float*)d_in[3];   // [256,256,3,3]
    const float* bias   = (const float*)d_in[4];   // [256]
    float* out = (float*)d_out;                    // [4,256,64,64]

    __bf16* wp = (__bf16*)d_ws;                    // 589824 bf16 = 1.18 MB

    prep_weights<<<288, 256, 0, stream>>>(weight, wp);
    dcn_main<<<256, 512, 0, stream>>>(x, off, msk, wp, bias, out);
}